// Round 1
// baseline (509.845 us; speedup 1.0000x reference)
//
#include <hip/hip_runtime.h>

// Problem constants (match reference)
#define BB   64
#define CCH  3
#define HH   640
#define WW   640
#define PHH  128
#define PWW  128

// ---------------------------------------------------------------------------
// Kernel 1: pure streaming copy, 1 float4 per thread (m13 pattern, ~6.3 TB/s).
// Total float4s = 64*3*640*640/4 = 19,660,800 = 76,800 blocks * 256 threads.
// ---------------------------------------------------------------------------
__global__ __launch_bounds__(256) void copy_kernel(
    const float4* __restrict__ src,
    float4* __restrict__ dst)
{
    size_t i = (size_t)blockIdx.x * 256 + threadIdx.x;
    dst[i] = src[i];
}

// ---------------------------------------------------------------------------
// Kernel 2: patch paste over the scaled/rotated rect only.
// Grid: (rows = 154, batches = 64), block = 192 threads (3 waves) covering x.
// sh,sw <= floor(128*1.2) = 153, so 154 rows / 192 cols always cover the rect.
// Math is copied verbatim from the verified fused kernel (passed absmax check).
// ---------------------------------------------------------------------------
__global__ __launch_bounds__(192) void patch_paste_kernel(
    const float* __restrict__ patch,
    const float* __restrict__ angles,
    const float* __restrict__ scales,
    const float* __restrict__ ux,
    const float* __restrict__ uy,
    float* __restrict__ out)
{
    const int b  = blockIdx.y;
    const int yy = blockIdx.x;      // row inside paste rect
    const int xx = threadIdx.x;     // col inside paste rect

    const float scale = scales[b];
    const float sh = floorf((float)PHH * scale);
    const float sw = floorf((float)PWW * scale);

    // whole-block-uniform row check, then per-lane col check
    if ((float)yy >= sh) return;
    if ((float)xx >= sw) return;

    const float y0f = floorf(uy[b] * ((float)HH - sh));
    const float x0f = floorf(ux[b] * ((float)WW - sw));
    const int y0i = (int)y0f;
    const int x0i = (int)x0f;

    const float theta = angles[b] * 0.017453292519943295f;  // deg2rad
    float si, co;
    sincosf(theta, &si, &co);
    const float rh = (float)PHH / sh;
    const float rw = (float)PWW / sw;
    const float cy = (PHH - 1) * 0.5f;
    const float cx = (PWW - 1) * 0.5f;

    // yl = yy, xl = xx (integer offsets inside the rect)
    const float yr = ((float)yy + 0.5f) * rh - 0.5f;
    const float xr = ((float)xx + 0.5f) * rw - 0.5f;
    const float dy = yr - cy;
    const float dx = xr - cx;

    // inverse rotation (same op order as reference)
    const float xp = co * dx + si * dy + cx;
    const float yp = -si * dx + co * dy + cy;

    const float yfl = floorf(yp);
    const float xfl = floorf(xp);
    const float wy = yp - yfl;
    const float wx = xp - xfl;
    const int yi = (int)yfl;
    const int xi = (int)xfl;

    const bool iy0 = (yi     >= 0) && (yi     <= PHH - 1);
    const bool iy1 = (yi + 1 >= 0) && (yi + 1 <= PHH - 1);
    const bool ix0 = (xi     >= 0) && (xi     <= PWW - 1);
    const bool ix1 = (xi + 1 >= 0) && (xi + 1 <= PWW - 1);

    const int yc0 = min(max(yi,     0), PHH - 1);
    const int yc1 = min(max(yi + 1, 0), PHH - 1);
    const int xc0 = min(max(xi,     0), PWW - 1);
    const int xc1 = min(max(xi + 1, 0), PWW - 1);

    const float w00 = ((1.0f - wy) * (1.0f - wx)) * ((iy0 && ix0) ? 1.0f : 0.0f);
    const float w01 = ((1.0f - wy) * wx)          * ((iy0 && ix1) ? 1.0f : 0.0f);
    const float w10 = (wy * (1.0f - wx))          * ((iy1 && ix0) ? 1.0f : 0.0f);
    const float w11 = (wy * wx)                   * ((iy1 && ix1) ? 1.0f : 0.0f);

    const int o00 = yc0 * PWW + xc0;
    const int o01 = yc0 * PWW + xc1;
    const int o10 = yc1 * PWW + xc0;
    const int o11 = yc1 * PWW + xc1;

    const size_t plane = (size_t)HH * WW;
    const size_t base  = (size_t)b * CCH * plane
                       + (size_t)(y0i + yy) * WW + (x0i + xx);

    #pragma unroll
    for (int c = 0; c < 3; ++c) {
        const float* p = patch + c * (PHH * PWW);
        float s = p[o00] * w00 + p[o01] * w01
                + p[o10] * w10 + p[o11] * w11;
        out[base + (size_t)c * plane] = s;
    }
}

extern "C" void kernel_launch(void* const* d_in, const int* in_sizes, int n_in,
                              void* d_out, int out_size, void* d_ws, size_t ws_size,
                              hipStream_t stream) {
    const float* images = (const float*)d_in[0];
    const float* patch  = (const float*)d_in[1];
    const float* angles = (const float*)d_in[2];
    const float* scales = (const float*)d_in[3];
    const float* ux     = (const float*)d_in[4];
    const float* uy     = (const float*)d_in[5];
    float* out = (float*)d_out;

    // 1) full-image copy: 19,660,800 float4s -> 76,800 blocks of 256
    const int n_f4    = BB * CCH * HH * WW / 4;   // 19,660,800
    const int cblocks = n_f4 / 256;               // 76,800 (exact)
    copy_kernel<<<cblocks, 256, 0, stream>>>(
        (const float4*)images, (float4*)out);

    // 2) paste the transformed patch (stream-ordered after the copy)
    dim3 pgrid(154, BB);
    patch_paste_kernel<<<pgrid, 192, 0, stream>>>(
        patch, angles, scales, ux, uy, out);
}